// Round 8
// baseline (1906.456 us; speedup 1.0000x reference)
//
#include <hip/hip_runtime.h>

// VQ codebook nearest-neighbor: xs [32768,512] f32, W [8192,512] f32
// out[i] = W[argmin_j ||xs_i - W_j||^2]
//
// R8: f16 MFMA approx pass, 256x256 tile, FOUR waves (2x2), per-wave output
//     128x128 (8Mx8N frags, acc in 256 AGPRs) -> 16 ds_read_b128 per 64 MFMA
//     (0.25 KB/MFMA, half of R7). 2-phase dbuf (2x32KB=64KB LDS) -> 2 blocks/CU
//     for cross-block overlap. + lean u32 best-2 epilogue + exact fp32 fixup.

#define M_TOK 32768
#define N_EMB 8192
#define D_K   512
#define WOFF  2048.0f
#define QMASK 0xFFFFFF00u     // 8 low bits = local col; quant step 0.0625
#define BAND  0.375f
#define NT    16              // K-tiles of 32

typedef _Float16 f16;
typedef __attribute__((ext_vector_type(8))) _Float16 f16x8;
typedef __attribute__((ext_vector_type(4))) _Float16 f16x4;
typedef __attribute__((ext_vector_type(4))) float f32x4;
typedef unsigned long long u64;
typedef unsigned int u32;

__device__ __forceinline__ void gload16(const void* g, void* l) {
  __builtin_amdgcn_global_load_lds(
      (const __attribute__((address_space(1))) unsigned int*)g,
      (__attribute__((address_space(3))) unsigned int*)l, 16, 0, 0);
}

__device__ __forceinline__ u32 map_f(float f) {   // exact order-preserving (fixup)
  u32 u = __float_as_uint(f);
  return u ^ ((u & 0x80000000u) ? 0xFFFFFFFFu : 0x80000000u);
}
__device__ __forceinline__ float qval(u32 key) {  // quantized approx value
  return __uint_as_float(key & QMASK) - WOFF;
}

// ---------------- fp32 -> f16 X (round-nearest) ----------------
__global__ __launch_bounds__(256) void convert_hi_kernel(const float* __restrict__ src,
                                                         f16* __restrict__ dst, int n4) {
  int e = blockIdx.x * 256 + threadIdx.x;
  if (e >= n4) return;
  float4 v = ((const float4*)src)[e];
  f16x4 h; h.x = (f16)v.x; h.y = (f16)v.y; h.z = (f16)v.z; h.w = (f16)v.w;
  *(f16x4*)(dst + (size_t)e * 4) = h;
}

// ---------------- W: convert + ||w||^2 fused (one wave per row) ----------------
__global__ __launch_bounds__(256) void convw_norm_kernel(const float* __restrict__ w,
                                                         f16* __restrict__ Wh,
                                                         float* __restrict__ wnorm,
                                                         int* __restrict__ cnt) {
  if (blockIdx.x == 0 && threadIdx.x == 0) *cnt = 0;
  const int row  = blockIdx.x * 4 + (threadIdx.x >> 6);
  const int lane = threadIdx.x & 63;
  const float4* wr = (const float4*)(w + (size_t)row * D_K);
  float4 v0 = wr[lane * 2], v1 = wr[lane * 2 + 1];
  f16x8 h;
  h[0] = (f16)v0.x; h[1] = (f16)v0.y; h[2] = (f16)v0.z; h[3] = (f16)v0.w;
  h[4] = (f16)v1.x; h[5] = (f16)v1.y; h[6] = (f16)v1.z; h[7] = (f16)v1.w;
  *(f16x8*)(Wh + (size_t)row * D_K + lane * 8) = h;
  float s = v0.x*v0.x + v0.y*v0.y + v0.z*v0.z + v0.w*v0.w
          + v1.x*v1.x + v1.y*v1.y + v1.z*v1.z + v1.w*v1.w;
  #pragma unroll
  for (int off = 32; off; off >>= 1) s += __shfl_xor(s, off);
  if (lane == 0) wnorm[row] = s;
}

// ---------------- approx distance + per-block best-2 ----------------
// 256x256 tile, 4 waves (2x2), per-wave 128x128, BK=32, dbuf 2x32KB.
// Per tile: stage(t+1)->other buf; 16 ds_read; 64 MFMA; vmcnt(0)+lgkm(0)+bar.
// Buf safety: buf (t+1)&1 held tile t-1; its reads drained (lgkmcnt 0) before
// iter t-1's end barrier; stages are issued after that barrier -> no WAR race.
__global__ __launch_bounds__(256, 2) void dist_mfma_kernel(
    const f16* __restrict__ Xh, const f16* __restrict__ Wh,
    const float* __restrict__ wnorm, uint2* __restrict__ partials) {
  __shared__ char smem[65536];   // buf b at b*32768: [A 16KB | B 16KB]

  int bid = (int)blockIdx.x;
  bid = (bid & 7) * 512 + (bid >> 3);           // XCD swizzle (4096 % 8 == 0)
  const int rt = bid >> 5, ct = bid & 31;
  const int row0 = rt * 256, col0 = ct * 256;

  const int tid  = threadIdx.x;
  const int w    = tid >> 6, lane = tid & 63;
  const int wr   = w >> 1,  wc   = w & 1;       // 2x2 wave grid
  const int g    = lane >> 4, cl = lane & 15;

  const char* gA = (const char*)Xh + (size_t)row0 * 1024;   // row = 1024 B
  const char* gB = (const char*)Wh + (size_t)col0 * 1024;

  // stage source offsets (pre-swizzled). chunk c = q*256 + w*64 + lane (16B);
  // tile row r = c>>2, dest slot s = c&3 holds source k-granule s ^ (r&3).
  int srcoff[4];
  #pragma unroll
  for (int q = 0; q < 4; ++q) {
    const int c = q * 256 + w * 64 + lane;
    const int r = c >> 2;
    srcoff[q] = r * 1024 + ((c & 3) ^ (r & 3)) * 16;
  }

  // LDS read byte-offsets (within a buffer). Row stride 64B; slot g ^ (row&3).
  int offA[8], offB[8];
  #pragma unroll
  for (int m = 0; m < 8; ++m) {
    const int rl = wr * 128 + m * 16 + cl;
    offA[m] = rl * 64 + ((g ^ (rl & 3)) * 16);
  }
  #pragma unroll
  for (int n = 0; n < 8; ++n) {
    const int rl = wc * 128 + n * 16 + cl;
    offB[n] = 16384 + rl * 64 + ((g ^ (rl & 3)) * 16);
  }

  #define STG(bo, kt)                                                          \
    { _Pragma("unroll") for (int q = 0; q < 4; ++q) {                          \
        gload16(gA + srcoff[q] + (kt) * 64, smem + (bo) + q * 4096 + w * 1024);\
        gload16(gB + srcoff[q] + (kt) * 64,                                    \
                smem + (bo) + 16384 + q * 4096 + w * 1024); } }

  f32x4 acc[8][8];
  #pragma unroll
  for (int i = 0; i < 8; i++)
    #pragma unroll
    for (int j = 0; j < 8; j++) acc[i][j] = (f32x4)(0.0f);

  STG(0, 0);
  asm volatile("s_waitcnt vmcnt(0)\ns_barrier" ::: "memory");

  for (int t = 0; t < NT; ++t) {
    const int rb = (t & 1) * 32768, sb = rb ^ 32768;
    if (t < NT - 1) STG(sb, t + 1);

    f16x8 a[8], b[8];
    #pragma unroll
    for (int m = 0; m < 4; ++m) a[m] = *(const f16x8*)(smem + rb + offA[m]);
    #pragma unroll
    for (int n = 0; n < 4; ++n) b[n] = *(const f16x8*)(smem + rb + offB[n]);
    #pragma unroll
    for (int m = 4; m < 8; ++m) a[m] = *(const f16x8*)(smem + rb + offA[m]);
    #pragma unroll
    for (int n = 4; n < 8; ++n) b[n] = *(const f16x8*)(smem + rb + offB[n]);

    __builtin_amdgcn_s_setprio(1);
    #pragma unroll
    for (int m = 0; m < 8; ++m)
      #pragma unroll
      for (int n = 0; n < 8; ++n)
        acc[m][n] = __builtin_amdgcn_mfma_f32_16x16x32_f16(a[m], b[n], acc[m][n], 0, 0, 0);
    __builtin_amdgcn_s_setprio(0);

    asm volatile("s_waitcnt vmcnt(0) lgkmcnt(0)\ns_barrier" ::: "memory");
  }
  #undef STG

  // ---- epilogue: u32 keys (quantized bits | 8-bit local col), best-2 ----
  float wnp[8];
  u32 colb[8];
  #pragma unroll
  for (int n = 0; n < 8; ++n) {
    const int colL = wc * 128 + n * 16 + cl;
    wnp[n]  = wnorm[col0 + colL] + WOFF;
    colb[n] = (u32)colL;
  }

  uint2* cmb = (uint2*)smem;   // [256 rows][2 wc] = 4KB (loop fully drained)

  #pragma unroll
  for (int m = 0; m < 8; ++m) {
    #pragma unroll
    for (int r = 0; r < 4; ++r) {
      u32 k[8];
      #pragma unroll
      for (int n = 0; n < 8; ++n) {
        float s = fmaf(-2.0f, acc[m][n][r], wnp[n]);
        k[n] = (__float_as_uint(s) & QMASK) | colb[n];
      }
      u32 a1 = min(k[0], k[1]), a2 = max(k[0], k[1]);
      u32 b1 = min(k[2], k[3]), b2 = max(k[2], k[3]);
      u32 q1 = min(a1, b1), q2 = min(max(a1, b1), min(a2, b2));
      a1 = min(k[4], k[5]); a2 = max(k[4], k[5]);
      b1 = min(k[6], k[7]); b2 = max(k[6], k[7]);
      u32 r1 = min(a1, b1), r2 = min(max(a1, b1), min(a2, b2));
      u32 c1 = min(q1, r1), c2 = min(max(q1, r1), min(q2, r2));
      #pragma unroll
      for (int off = 1; off < 16; off <<= 1) {
        u32 o1 = __shfl_xor(c1, off), o2 = __shfl_xor(c2, off);
        u32 n1 = min(c1, o1);
        c2 = min(min(c2, o2), max(c1, o1));
        c1 = n1;
      }
      if (cl == 0) cmb[(wr * 128 + m * 16 + g * 4 + r) * 2 + wc] = make_uint2(c1, c2);
    }
  }
  __syncthreads();
  if (tid < 256) {
    uint2 A = cmb[tid * 2], B = cmb[tid * 2 + 1];
    u32 c1 = min(A.x, B.x);
    u32 c2 = min(max(A.x, B.x), min(A.y, B.y));
    partials[(size_t)ct * M_TOK + row0 + tid] = make_uint2(c1, c2);
  }
}

// ---------------- global best-2 + flag near-ties ----------------
__global__ __launch_bounds__(256) void reduce_kernel(
    const uint2* __restrict__ partials, u32* __restrict__ bestkey,
    int* __restrict__ fidx, int* __restrict__ flaglist, int* __restrict__ cnt) {
  int t = blockIdx.x * 256 + threadIdx.x;
  if (t >= M_TOK) return;
  u32 b1 = 0xFFFFFFFFu, b2 = 0xFFFFFFFFu;
  int bidx = 0;
  for (int ct = 0; ct < 32; ++ct) {
    uint2 e = partials[(size_t)ct * M_TOK + t];
    if (e.x < b1) {
      b2 = min(b1, min(b2, e.y));
      b1 = e.x;
      bidx = ct * 256 + (int)(e.x & 255u);
    } else {
      b2 = min(b2, e.x);
    }
  }
  bestkey[t] = b1;
  fidx[t] = bidx;
  if (qval(b2) - qval(b1) < BAND) flaglist[atomicAdd(cnt, 1)] = t;
}

// ---------------- exact fp32 re-rank for flagged tokens ----------------
__global__ __launch_bounds__(256) void fixup_kernel(
    const float* __restrict__ xs, const float* __restrict__ w,
    const float* __restrict__ wnorm, const uint2* __restrict__ partials,
    const u32* __restrict__ bestkey, const int* __restrict__ flaglist,
    const int* __restrict__ cnt, int* __restrict__ fidx) {
  __shared__ int s_cand[8256];
  __shared__ int s_n;
  __shared__ u64 s_best;
  const int n_flag = *cnt;
  for (int ii = blockIdx.x; ii < n_flag; ii += gridDim.x) {
    const int t = flaglist[ii];
    if (threadIdx.x == 0) { s_n = 0; s_best = ~0ULL; }
    __syncthreads();
    const float thr = qval(bestkey[t]) + BAND;
    if (threadIdx.x < 32) {
      uint2 e = partials[(size_t)threadIdx.x * M_TOK + t];
      if (qval(e.x) <= thr)
        s_cand[atomicAdd(&s_n, 1)] = (int)threadIdx.x * 256 + (int)(e.x & 255u);
      if (qval(e.y) <= thr) {                // possible hidden 3rd: scan whole block
        int base = atomicAdd(&s_n, 256);
        for (int c = 0; c < 256; ++c) s_cand[base + c] = (int)threadIdx.x * 256 + c;
      }
    }
    __syncthreads();
    const int n = s_n;
    const int wid = threadIdx.x >> 6, lane = threadIdx.x & 63;
    for (int c = wid; c < n; c += 4) {
      const int j = s_cand[c];
      const float4* xr = (const float4*)(xs + (size_t)t * D_K);
      const float4* wr = (const float4*)(w + (size_t)j * D_K);
      float4 a0 = xr[lane * 2], a1 = xr[lane * 2 + 1];
      float4 b0 = wr[lane * 2], b1 = wr[lane * 2 + 1];
      float s = a0.x*b0.x + a0.y*b0.y + a0.z*b0.z + a0.w*b0.w
              + a1.x*b1.x + a1.y*b1.y + a1.z*b1.z + a1.w*b1.w;
      #pragma unroll
      for (int off = 32; off; off >>= 1) s += __shfl_xor(s, off);
      if (lane == 0) {
        float score = wnorm[j] - 2.0f * s;
        u64 k = ((u64)map_f(score) << 32) | (u32)j;
        atomicMin(&s_best, k);
      }
    }
    __syncthreads();
    if (threadIdx.x == 0) fidx[t] = (int)(s_best & 0xFFFFFFFFULL);
    __syncthreads();
  }
}

// ---------------- gather: out = xs + (W[idx] - xs) ----------------
__global__ __launch_bounds__(256) void gather_kernel(const float* __restrict__ xs,
                                                     const float* __restrict__ w,
                                                     const int* __restrict__ fidx,
                                                     float* __restrict__ out) {
  int e = blockIdx.x * 256 + threadIdx.x;
  int row = e >> 7, off = e & 127;
  float4 xv = ((const float4*)(xs + (size_t)row * D_K))[off];
  float4 wv = ((const float4*)(w  + (size_t)fidx[row] * D_K))[off];
  float4 o;
  o.x = xv.x + (wv.x - xv.x);
  o.y = xv.y + (wv.y - xv.y);
  o.z = xv.z + (wv.z - xv.z);
  o.w = xv.w + (wv.w - xv.w);
  ((float4*)out)[e] = o;
}

extern "C" void kernel_launch(void* const* d_in, const int* in_sizes, int n_in,
                              void* d_out, int out_size, void* d_ws, size_t ws_size,
                              hipStream_t stream) {
  const float* xs = (const float*)d_in[0];
  const float* w  = (const float*)d_in[1];
  float* out = (float*)d_out;

  // ws layout (~51 MB; ws proven >= 85 MB in R2)
  char* p = (char*)d_ws;
  f16*   Xh       = (f16*)p;                 p += (size_t)M_TOK * D_K * 2;
  f16*   Wh       = (f16*)p;                 p += (size_t)N_EMB * D_K * 2;
  float* wnorm    = (float*)p;               p += (size_t)N_EMB * 4;
  uint2* partials = (uint2*)p;               p += (size_t)32 * M_TOK * 8;
  u32*   bestkey  = (u32*)p;                 p += (size_t)M_TOK * 4;
  int*   fidx     = (int*)p;                 p += (size_t)M_TOK * 4;
  int*   flaglist = (int*)p;                 p += (size_t)M_TOK * 4;
  int*   cnt      = (int*)p;

  convert_hi_kernel<<<(M_TOK * 128) / 256, 256, 0, stream>>>(xs, Xh, M_TOK * 128);
  convw_norm_kernel<<<N_EMB / 4, 256, 0, stream>>>(w, Wh, wnorm, cnt);
  dist_mfma_kernel<<<(M_TOK / 256) * (N_EMB / 256), 256, 0, stream>>>(Xh, Wh, wnorm, partials);
  reduce_kernel<<<M_TOK / 256, 256, 0, stream>>>(partials, bestkey, fidx, flaglist, cnt);
  fixup_kernel<<<256, 256, 0, stream>>>(xs, w, wnorm, partials, bestkey, flaglist, cnt, fidx);
  gather_kernel<<<(M_TOK * (D_K / 4)) / 256, 256, 0, stream>>>(xs, w, fidx, out);
}

// Round 9
// 519.608 us; speedup vs baseline: 3.6690x; 3.6690x over previous
//
#include <hip/hip_runtime.h>

// VQ codebook nearest-neighbor: xs [32768,512] f32, W [8192,512] f32
// out[i] = W[argmin_j ||xs_i - W_j||^2]
//
// R9: f16 MFMA approx pass, 256x256 tile, 4 waves (2x2), per-wave 128x128
//     (acc = 256 regs; launch_bounds(256,1) -> 512-reg budget, NO spill,
//     1 wave/SIMD). Triple-buffered LDS (3x32KB). Per iter: stage(t+2),
//     prefetch ALL frags of t+1 (reads overlap MFMA(t) on separate pipes),
//     counted lgkmcnt(15), 64 MFMA, vmcnt(0)+barrier.
//     + lean u32 best-2 epilogue + exact fp32 fixup (R4/R6-proven).

#define M_TOK 32768
#define N_EMB 8192
#define D_K   512
#define WOFF  2048.0f
#define QMASK 0xFFFFFF00u     // 8 low bits = local col; quant step 0.0625
#define BAND  0.375f
#define NT    16              // K-tiles of 32

typedef _Float16 f16;
typedef __attribute__((ext_vector_type(8))) _Float16 f16x8;
typedef __attribute__((ext_vector_type(4))) _Float16 f16x4;
typedef __attribute__((ext_vector_type(4))) float f32x4;
typedef unsigned long long u64;
typedef unsigned int u32;

__device__ __forceinline__ void gload16(const void* g, void* l) {
  __builtin_amdgcn_global_load_lds(
      (const __attribute__((address_space(1))) unsigned int*)g,
      (__attribute__((address_space(3))) unsigned int*)l, 16, 0, 0);
}

__device__ __forceinline__ u32 map_f(float f) {   // exact order-preserving (fixup)
  u32 u = __float_as_uint(f);
  return u ^ ((u & 0x80000000u) ? 0xFFFFFFFFu : 0x80000000u);
}
__device__ __forceinline__ float qval(u32 key) {  // quantized approx value
  return __uint_as_float(key & QMASK) - WOFF;
}

// ---------------- fp32 -> f16 X (round-nearest) ----------------
__global__ __launch_bounds__(256) void convert_hi_kernel(const float* __restrict__ src,
                                                         f16* __restrict__ dst, int n4) {
  int e = blockIdx.x * 256 + threadIdx.x;
  if (e >= n4) return;
  float4 v = ((const float4*)src)[e];
  f16x4 h; h.x = (f16)v.x; h.y = (f16)v.y; h.z = (f16)v.z; h.w = (f16)v.w;
  *(f16x4*)(dst + (size_t)e * 4) = h;
}

// ---------------- W: convert + ||w||^2 fused ----------------
__global__ __launch_bounds__(256) void convw_norm_kernel(const float* __restrict__ w,
                                                         f16* __restrict__ Wh,
                                                         float* __restrict__ wnorm,
                                                         int* __restrict__ cnt) {
  if (blockIdx.x == 0 && threadIdx.x == 0) *cnt = 0;
  const int row  = blockIdx.x * 4 + (threadIdx.x >> 6);
  const int lane = threadIdx.x & 63;
  const float4* wr = (const float4*)(w + (size_t)row * D_K);
  float4 v0 = wr[lane * 2], v1 = wr[lane * 2 + 1];
  f16x8 h;
  h[0] = (f16)v0.x; h[1] = (f16)v0.y; h[2] = (f16)v0.z; h[3] = (f16)v0.w;
  h[4] = (f16)v1.x; h[5] = (f16)v1.y; h[6] = (f16)v1.z; h[7] = (f16)v1.w;
  *(f16x8*)(Wh + (size_t)row * D_K + lane * 8) = h;
  float s = v0.x*v0.x + v0.y*v0.y + v0.z*v0.z + v0.w*v0.w
          + v1.x*v1.x + v1.y*v1.y + v1.z*v1.z + v1.w*v1.w;
  #pragma unroll
  for (int off = 32; off; off >>= 1) s += __shfl_xor(s, off);
  if (lane == 0) wnorm[row] = s;
}

// ---------------- approx distance + per-block best-2 ----------------
// Buffer ledger: buf X%3 holds tile X; frag-read during iter X-1; drained by
// iter X's lgkmcnt; overwritten by stage(X+3) issued iter X+1 (>=1 barrier gap).
// vmcnt(0) at iter end covers stage(t+2) issued ~1242 cyc earlier (hidden).
__global__ __launch_bounds__(256, 1) void dist_mfma_kernel(
    const f16* __restrict__ Xh, const f16* __restrict__ Wh,
    const float* __restrict__ wnorm, uint2* __restrict__ partials) {
  __shared__ char smem[98304];   // 3 bufs x [A 16KB | B 16KB]

  int bid = (int)blockIdx.x;
  bid = (bid & 7) * 512 + (bid >> 3);           // XCD swizzle (4096 % 8 == 0)
  const int rt = bid >> 5, ct = bid & 31;
  const int row0 = rt * 256, col0 = ct * 256;

  const int tid  = threadIdx.x;
  const int w    = tid >> 6, lane = tid & 63;
  const int wr   = w >> 1,  wc   = w & 1;       // 2x2 wave grid
  const int g    = lane >> 4, cl = lane & 15;

  const char* gA = (const char*)Xh + (size_t)row0 * 1024;   // row = 1024 B
  const char* gB = (const char*)Wh + (size_t)col0 * 1024;

  // stage source offsets (pre-swizzled, R7-proven (r>>1)&3 pattern)
  int srcoff[4];
  #pragma unroll
  for (int q = 0; q < 4; ++q) {
    const int c = q * 256 + w * 64 + lane;      // 16B chunk id
    const int r = c >> 2;                       // tile row
    srcoff[q] = r * 1024 + (((c & 3) ^ ((r >> 1) & 3)) * 16);
  }

  // LDS frag-read offsets (row stride 64B, slot g ^ ((row>>1)&3))
  int offA[8], offB[8];
  #pragma unroll
  for (int m = 0; m < 8; ++m) {
    const int rl = wr * 128 + m * 16 + cl;
    offA[m] = rl * 64 + ((g ^ ((rl >> 1) & 3)) * 16);
  }
  #pragma unroll
  for (int n = 0; n < 8; ++n) {
    const int rl = wc * 128 + n * 16 + cl;
    offB[n] = 16384 + rl * 64 + ((g ^ ((rl >> 1) & 3)) * 16);
  }

  #define STG(bo, kt)                                                          \
    { _Pragma("unroll") for (int q = 0; q < 4; ++q) {                          \
        gload16(gA + srcoff[q] + (kt) * 64, smem + (bo) + q * 4096 + w * 1024);\
        gload16(gB + srcoff[q] + (kt) * 64,                                    \
                smem + (bo) + 16384 + q * 4096 + w * 1024); } }

  #define RDFRAG(fb, A_, B_)                                                   \
    { _Pragma("unroll") for (int m = 0; m < 8; ++m)                            \
        A_[m] = *(const f16x8*)(smem + (fb) + offA[m]);                        \
      _Pragma("unroll") for (int n = 0; n < 8; ++n)                            \
        B_[n] = *(const f16x8*)(smem + (fb) + offB[n]); }

  f32x4 acc[8][8];
  #pragma unroll
  for (int i = 0; i < 8; i++)
    #pragma unroll
    for (int j = 0; j < 8; j++) acc[i][j] = (f32x4)(0.0f);

  // prologue: stage tiles 0,1; drain; read tile-0 frags (left in flight)
  STG(0, 0);
  STG(32768, 1);
  asm volatile("s_waitcnt vmcnt(0)\ns_barrier" ::: "memory");

  f16x8 aP[8], bP[8], aQ[8], bQ[8];
  RDFRAG(0, aP, bP);

  #define TILE(t, CA, CB, NA, NB)                                              \
    {                                                                          \
      constexpr int fb = (((t) + 1) % 3) * 32768;                              \
      constexpr int sb = (((t) + 2) % 3) * 32768;                              \
      if ((t) + 2 < NT) STG(sb, (t) + 2);                                      \
      if ((t) < NT - 1) RDFRAG(fb, NA, NB);                                    \
      if ((t) < NT - 1) { asm volatile("s_waitcnt lgkmcnt(15)" ::: "memory"); }\
      else              { asm volatile("s_waitcnt lgkmcnt(0)" ::: "memory"); } \
      __builtin_amdgcn_sched_barrier(0);                                       \
      _Pragma("unroll") for (int m = 0; m < 8; ++m)                            \
        _Pragma("unroll") for (int n = 0; n < 8; ++n)                          \
          acc[m][n] = __builtin_amdgcn_mfma_f32_16x16x32_f16(CA[m], CB[n], acc[m][n], 0, 0, 0); \
      asm volatile("s_waitcnt vmcnt(0)\ns_barrier" ::: "memory");              \
    }

  TILE(0,  aP, bP, aQ, bQ)  TILE(1,  aQ, bQ, aP, bP)
  TILE(2,  aP, bP, aQ, bQ)  TILE(3,  aQ, bQ, aP, bP)
  TILE(4,  aP, bP, aQ, bQ)  TILE(5,  aQ, bQ, aP, bP)
  TILE(6,  aP, bP, aQ, bQ)  TILE(7,  aQ, bQ, aP, bP)
  TILE(8,  aP, bP, aQ, bQ)  TILE(9,  aQ, bQ, aP, bP)
  TILE(10, aP, bP, aQ, bQ)  TILE(11, aQ, bQ, aP, bP)
  TILE(12, aP, bP, aQ, bQ)  TILE(13, aQ, bQ, aP, bP)
  TILE(14, aP, bP, aQ, bQ)  TILE(15, aQ, bQ, aP, bP)

  #undef TILE
  #undef RDFRAG
  #undef STG

  // ---- epilogue: u32 keys (quantized bits | 8-bit local col), best-2 ----
  float wnp[8];
  u32 colb[8];
  #pragma unroll
  for (int n = 0; n < 8; ++n) {
    const int colL = wc * 128 + n * 16 + cl;
    wnp[n]  = wnorm[col0 + colL] + WOFF;
    colb[n] = (u32)colL;
  }

  uint2* cmb = (uint2*)smem;   // [256 rows][2 wc] = 4KB (loop fully drained)

  #pragma unroll
  for (int m = 0; m < 8; ++m) {
    #pragma unroll
    for (int r = 0; r < 4; ++r) {
      u32 k[8];
      #pragma unroll
      for (int n = 0; n < 8; ++n) {
        float s = fmaf(-2.0f, acc[m][n][r], wnp[n]);
        k[n] = (__float_as_uint(s) & QMASK) | colb[n];
      }
      u32 a1 = min(k[0], k[1]), a2 = max(k[0], k[1]);
      u32 b1 = min(k[2], k[3]), b2 = max(k[2], k[3]);
      u32 q1 = min(a1, b1), q2 = min(max(a1, b1), min(a2, b2));
      a1 = min(k[4], k[5]); a2 = max(k[4], k[5]);
      b1 = min(k[6], k[7]); b2 = max(k[6], k[7]);
      u32 r1 = min(a1, b1), r2 = min(max(a1, b1), min(a2, b2));
      u32 c1 = min(q1, r1), c2 = min(max(q1, r1), min(q2, r2));
      #pragma unroll
      for (int off = 1; off < 16; off <<= 1) {
        u32 o1 = __shfl_xor(c1, off), o2 = __shfl_xor(c2, off);
        u32 n1 = min(c1, o1);
        c2 = min(min(c2, o2), max(c1, o1));
        c1 = n1;
      }
      if (cl == 0) cmb[(wr * 128 + m * 16 + g * 4 + r) * 2 + wc] = make_uint2(c1, c2);
    }
  }
  __syncthreads();
  if (tid < 256) {
    uint2 A = cmb[tid * 2], B = cmb[tid * 2 + 1];
    u32 c1 = min(A.x, B.x);
    u32 c2 = min(max(A.x, B.x), min(A.y, B.y));
    partials[(size_t)ct * M_TOK + row0 + tid] = make_uint2(c1, c2);
  }
}

// ---------------- global best-2 + flag near-ties ----------------
__global__ __launch_bounds__(256) void reduce_kernel(
    const uint2* __restrict__ partials, u32* __restrict__ bestkey,
    int* __restrict__ fidx, int* __restrict__ flaglist, int* __restrict__ cnt) {
  int t = blockIdx.x * 256 + threadIdx.x;
  if (t >= M_TOK) return;
  u32 b1 = 0xFFFFFFFFu, b2 = 0xFFFFFFFFu;
  int bidx = 0;
  for (int ct = 0; ct < 32; ++ct) {
    uint2 e = partials[(size_t)ct * M_TOK + t];
    if (e.x < b1) {
      b2 = min(b1, min(b2, e.y));
      b1 = e.x;
      bidx = ct * 256 + (int)(e.x & 255u);
    } else {
      b2 = min(b2, e.x);
    }
  }
  bestkey[t] = b1;
  fidx[t] = bidx;
  if (qval(b2) - qval(b1) < BAND) flaglist[atomicAdd(cnt, 1)] = t;
}

// ---------------- exact fp32 re-rank for flagged tokens ----------------
__global__ __launch_bounds__(256) void fixup_kernel(
    const float* __restrict__ xs, const float* __restrict__ w,
    const float* __restrict__ wnorm, const uint2* __restrict__ partials,
    const u32* __restrict__ bestkey, const int* __restrict__ flaglist,
    const int* __restrict__ cnt, int* __restrict__ fidx) {
  __shared__ int s_cand[8256];
  __shared__ int s_n;
  __shared__ u64 s_best;
  const int n_flag = *cnt;
  for (int ii = blockIdx.x; ii < n_flag; ii += gridDim.x) {
    const int t = flaglist[ii];
    if (threadIdx.x == 0) { s_n = 0; s_best = ~0ULL; }
    __syncthreads();
    const float thr = qval(bestkey[t]) + BAND;
    if (threadIdx.x < 32) {
      uint2 e = partials[(size_t)threadIdx.x * M_TOK + t];
      if (qval(e.x) <= thr)
        s_cand[atomicAdd(&s_n, 1)] = (int)threadIdx.x * 256 + (int)(e.x & 255u);
      if (qval(e.y) <= thr) {                // possible hidden 3rd: scan whole block
        int base = atomicAdd(&s_n, 256);
        for (int c = 0; c < 256; ++c) s_cand[base + c] = (int)threadIdx.x * 256 + c;
      }
    }
    __syncthreads();
    const int n = s_n;
    const int wid = threadIdx.x >> 6, lane = threadIdx.x & 63;
    for (int c = wid; c < n; c += 4) {
      const int j = s_cand[c];
      const float4* xr = (const float4*)(xs + (size_t)t * D_K);
      const float4* wr = (const float4*)(w + (size_t)j * D_K);
      float4 a0 = xr[lane * 2], a1 = xr[lane * 2 + 1];
      float4 b0 = wr[lane * 2], b1 = wr[lane * 2 + 1];
      float s = a0.x*b0.x + a0.y*b0.y + a0.z*b0.z + a0.w*b0.w
              + a1.x*b1.x + a1.y*b1.y + a1.z*b1.z + a1.w*b1.w;
      #pragma unroll
      for (int off = 32; off; off >>= 1) s += __shfl_xor(s, off);
      if (lane == 0) {
        float score = wnorm[j] - 2.0f * s;
        u64 k = ((u64)map_f(score) << 32) | (u32)j;
        atomicMin(&s_best, k);
      }
    }
    __syncthreads();
    if (threadIdx.x == 0) fidx[t] = (int)(s_best & 0xFFFFFFFFULL);
    __syncthreads();
  }
}

// ---------------- gather: out = xs + (W[idx] - xs) ----------------
__global__ __launch_bounds__(256) void gather_kernel(const float* __restrict__ xs,
                                                     const float* __restrict__ w,
                                                     const int* __restrict__ fidx,
                                                     float* __restrict__ out) {
  int e = blockIdx.x * 256 + threadIdx.x;
  int row = e >> 7, off = e & 127;
  float4 xv = ((const float4*)(xs + (size_t)row * D_K))[off];
  float4 wv = ((const float4*)(w  + (size_t)fidx[row] * D_K))[off];
  float4 o;
  o.x = xv.x + (wv.x - xv.x);
  o.y = xv.y + (wv.y - xv.y);
  o.z = xv.z + (wv.z - xv.z);
  o.w = xv.w + (wv.w - xv.w);
  ((float4*)out)[e] = o;
}

extern "C" void kernel_launch(void* const* d_in, const int* in_sizes, int n_in,
                              void* d_out, int out_size, void* d_ws, size_t ws_size,
                              hipStream_t stream) {
  const float* xs = (const float*)d_in[0];
  const float* w  = (const float*)d_in[1];
  float* out = (float*)d_out;

  // ws layout (~51 MB; ws proven >= 85 MB in R2)
  char* p = (char*)d_ws;
  f16*   Xh       = (f16*)p;                 p += (size_t)M_TOK * D_K * 2;
  f16*   Wh       = (f16*)p;                 p += (size_t)N_EMB * D_K * 2;
  float* wnorm    = (float*)p;               p += (size_t)N_EMB * 4;
  uint2* partials = (uint2*)p;               p += (size_t)32 * M_TOK * 8;
  u32*   bestkey  = (u32*)p;                 p += (size_t)M_TOK * 4;
  int*   fidx     = (int*)p;                 p += (size_t)M_TOK * 4;
  int*   flaglist = (int*)p;                 p += (size_t)M_TOK * 4;
  int*   cnt      = (int*)p;

  convert_hi_kernel<<<(M_TOK * 128) / 256, 256, 0, stream>>>(xs, Xh, M_TOK * 128);
  convw_norm_kernel<<<N_EMB / 4, 256, 0, stream>>>(w, Wh, wnorm, cnt);
  dist_mfma_kernel<<<(M_TOK / 256) * (N_EMB / 256), 256, 0, stream>>>(Xh, Wh, wnorm, partials);
  reduce_kernel<<<M_TOK / 256, 256, 0, stream>>>(partials, bestkey, fidx, flaglist, cnt);
  fixup_kernel<<<256, 256, 0, stream>>>(xs, w, wnorm, partials, bestkey, flaglist, cnt, fidx);
  gather_kernel<<<(M_TOK * (D_K / 4)) / 256, 256, 0, stream>>>(xs, w, fidx, out);
}

// Round 10
// 507.605 us; speedup vs baseline: 3.7558x; 1.0236x over previous
//
#include <hip/hip_runtime.h>

// VQ codebook nearest-neighbor: xs [32768,512] f32, W [8192,512] f32
// out[i] = W[argmin_j ||xs_i - W_j||^2]
//
// R10: f16 MFMA approx pass. Tile 128x256, 4 waves (1M x 4N), wave-tile
//      128x64 (acc 128 AGPR, ~120 VGPR -> true 2 waves/SIMD via
//      launch_bounds(256,2)). Dbuf 2x24KB=48KB LDS -> 2 blocks/CU:
//      cross-block overlap hides stage/barrier stalls (R2-proven regime,
//      m114). Simple 1-barrier/K-step loop - no exotic scheduling.
//      + lean u32 best-2 epilogue + exact fp32 fixup (R4/R6-proven).

#define M_TOK 32768
#define N_EMB 8192
#define D_K   512
#define WOFF  2048.0f
#define QMASK 0xFFFFFF00u     // 8 low bits = local col; quant step 0.0625
#define BAND  0.375f
#define NT    16              // K-tiles of 32

typedef _Float16 f16;
typedef __attribute__((ext_vector_type(8))) _Float16 f16x8;
typedef __attribute__((ext_vector_type(4))) _Float16 f16x4;
typedef __attribute__((ext_vector_type(4))) float f32x4;
typedef unsigned long long u64;
typedef unsigned int u32;

__device__ __forceinline__ void gload16(const void* g, void* l) {
  __builtin_amdgcn_global_load_lds(
      (const __attribute__((address_space(1))) unsigned int*)g,
      (__attribute__((address_space(3))) unsigned int*)l, 16, 0, 0);
}

__device__ __forceinline__ u32 map_f(float f) {   // exact order-preserving (fixup)
  u32 u = __float_as_uint(f);
  return u ^ ((u & 0x80000000u) ? 0xFFFFFFFFu : 0x80000000u);
}
__device__ __forceinline__ float qval(u32 key) {  // quantized approx value
  return __uint_as_float(key & QMASK) - WOFF;
}

// ---------------- fp32 -> f16 X (round-nearest) ----------------
__global__ __launch_bounds__(256) void convert_hi_kernel(const float* __restrict__ src,
                                                         f16* __restrict__ dst, int n4) {
  int e = blockIdx.x * 256 + threadIdx.x;
  if (e >= n4) return;
  float4 v = ((const float4*)src)[e];
  f16x4 h; h.x = (f16)v.x; h.y = (f16)v.y; h.z = (f16)v.z; h.w = (f16)v.w;
  *(f16x4*)(dst + (size_t)e * 4) = h;
}

// ---------------- W: convert + ||w||^2 fused ----------------
__global__ __launch_bounds__(256) void convw_norm_kernel(const float* __restrict__ w,
                                                         f16* __restrict__ Wh,
                                                         float* __restrict__ wnorm,
                                                         int* __restrict__ cnt) {
  if (blockIdx.x == 0 && threadIdx.x == 0) *cnt = 0;
  const int row  = blockIdx.x * 4 + (threadIdx.x >> 6);
  const int lane = threadIdx.x & 63;
  const float4* wr = (const float4*)(w + (size_t)row * D_K);
  float4 v0 = wr[lane * 2], v1 = wr[lane * 2 + 1];
  f16x8 h;
  h[0] = (f16)v0.x; h[1] = (f16)v0.y; h[2] = (f16)v0.z; h[3] = (f16)v0.w;
  h[4] = (f16)v1.x; h[5] = (f16)v1.y; h[6] = (f16)v1.z; h[7] = (f16)v1.w;
  *(f16x8*)(Wh + (size_t)row * D_K + lane * 8) = h;
  float s = v0.x*v0.x + v0.y*v0.y + v0.z*v0.z + v0.w*v0.w
          + v1.x*v1.x + v1.y*v1.y + v1.z*v1.z + v1.w*v1.w;
  #pragma unroll
  for (int off = 32; off; off >>= 1) s += __shfl_xor(s, off);
  if (lane == 0) wnorm[row] = s;
}

// ---------------- approx distance + per-block best-2 ----------------
// Dbuf safety: stage(t+1)->buf^1 whose reads (iter t-1) were drained by
// iter t-1's __syncthreads (vmcnt0+lgkm0+barrier); stage issued after it.
__global__ __launch_bounds__(256, 2) void dist_mfma_kernel(
    const f16* __restrict__ Xh, const f16* __restrict__ Wh,
    const float* __restrict__ wnorm, uint2* __restrict__ partials) {
  __shared__ char smem[49152];   // buf b at b*24576: [A 8KB | B 16KB]

  int bid = (int)blockIdx.x;
  const int swz = (bid & 7) * 1024 + (bid >> 3);   // XCD swizzle (8192 % 8 == 0)
  const int rt = swz & 255, ct = swz >> 8;          // rt fast -> B-panel L2 reuse
  const int row0 = rt * 128, col0 = ct * 256;

  const int tid  = threadIdx.x;
  const int w    = tid >> 6, lane = tid & 63;       // 4 N-waves
  const int g    = lane >> 4, cl = lane & 15;

  const char* gA = (const char*)Xh + (size_t)row0 * 1024;   // row = 1024 B
  const char* gB = (const char*)Wh + (size_t)col0 * 1024;

  // stage source offsets (pre-swizzled, R2/R9-proven (r>>1)&3 pattern)
  int srcA[2], srcB[4];
  #pragma unroll
  for (int q = 0; q < 2; ++q) {
    const int c = q * 256 + tid;                    // A chunk 0..511
    const int r = c >> 2;
    srcA[q] = r * 1024 + (((c & 3) ^ ((r >> 1) & 3)) * 16);
  }
  #pragma unroll
  for (int q = 0; q < 4; ++q) {
    const int c = q * 256 + tid;                    // B chunk 0..1023
    const int r = c >> 2;
    srcB[q] = r * 1024 + (((c & 3) ^ ((r >> 1) & 3)) * 16);
  }

  // LDS frag-read offsets (row stride 64B, slot g ^ ((row>>1)&3))
  int offA[8], offB[4];
  #pragma unroll
  for (int m = 0; m < 8; ++m) {
    const int rl = m * 16 + cl;                     // all 128 A-rows per wave
    offA[m] = rl * 64 + ((g ^ ((rl >> 1) & 3)) * 16);
  }
  #pragma unroll
  for (int n = 0; n < 4; ++n) {
    const int rl = w * 64 + n * 16 + cl;            // wave's 64 B-rows
    offB[n] = 8192 + rl * 64 + ((g ^ ((rl >> 1) & 3)) * 16);
  }

  #define STG(bo, kt)                                                          \
    { _Pragma("unroll") for (int q = 0; q < 2; ++q)                            \
        gload16(gA + srcA[q] + (kt) * 64, smem + (bo) + q * 4096 + w * 1024);  \
      _Pragma("unroll") for (int q = 0; q < 4; ++q)                            \
        gload16(gB + srcB[q] + (kt) * 64,                                      \
                smem + (bo) + 8192 + q * 4096 + w * 1024); }

  f32x4 acc[8][4];
  #pragma unroll
  for (int i = 0; i < 8; i++)
    #pragma unroll
    for (int j = 0; j < 4; j++) acc[i][j] = (f32x4)(0.0f);

  STG(0, 0);
  __syncthreads();

  for (int t = 0; t < NT; ++t) {
    const int rb = (t & 1) * 24576, sb = rb ^ 24576;
    if (t < NT - 1) STG(sb, t + 1);

    f16x8 a[8], b[4];
    #pragma unroll
    for (int m = 0; m < 8; ++m) a[m] = *(const f16x8*)(smem + rb + offA[m]);
    #pragma unroll
    for (int n = 0; n < 4; ++n) b[n] = *(const f16x8*)(smem + rb + offB[n]);

    __builtin_amdgcn_s_setprio(1);
    #pragma unroll
    for (int m = 0; m < 8; ++m)
      #pragma unroll
      for (int n = 0; n < 4; ++n)
        acc[m][n] = __builtin_amdgcn_mfma_f32_16x16x32_f16(a[m], b[n], acc[m][n], 0, 0, 0);
    __builtin_amdgcn_s_setprio(0);

    __syncthreads();   // drains vmcnt (stage landed) + lgkm (buf reads done)
  }
  #undef STG

  // ---- epilogue: u32 keys (quantized bits | 8-bit local col), best-2 ----
  float wnp[4];
  u32 colb[4];
  #pragma unroll
  for (int n = 0; n < 4; ++n) {
    const int colL = w * 64 + n * 16 + cl;
    wnp[n]  = wnorm[col0 + colL] + WOFF;
    colb[n] = (u32)colL;
  }

  uint2* cmb = (uint2*)smem;   // [128 rows][4 waves] = 4KB

  #pragma unroll
  for (int m = 0; m < 8; ++m) {
    #pragma unroll
    for (int r = 0; r < 4; ++r) {
      float s0 = fmaf(-2.0f, acc[m][0][r], wnp[0]);
      float s1 = fmaf(-2.0f, acc[m][1][r], wnp[1]);
      float s2 = fmaf(-2.0f, acc[m][2][r], wnp[2]);
      float s3 = fmaf(-2.0f, acc[m][3][r], wnp[3]);
      u32 k0 = (__float_as_uint(s0) & QMASK) | colb[0];
      u32 k1 = (__float_as_uint(s1) & QMASK) | colb[1];
      u32 k2 = (__float_as_uint(s2) & QMASK) | colb[2];
      u32 k3 = (__float_as_uint(s3) & QMASK) | colb[3];
      u32 pa = min(k0, k1), pb = max(k0, k1);
      u32 pc = min(k2, k3), pd = max(k2, k3);
      u32 c1 = min(pa, pc);
      u32 c2 = min(max(pa, pc), min(pb, pd));
      #pragma unroll
      for (int off = 1; off < 16; off <<= 1) {
        u32 o1 = __shfl_xor(c1, off), o2 = __shfl_xor(c2, off);
        u32 n1 = min(c1, o1);
        c2 = min(min(c2, o2), max(c1, o1));
        c1 = n1;
      }
      if (cl == 0) cmb[(m * 16 + g * 4 + r) * 4 + w] = make_uint2(c1, c2);
    }
  }
  __syncthreads();
  if (tid < 128) {
    u32 b1 = 0xFFFFFFFFu, b2 = 0xFFFFFFFFu;
    #pragma unroll
    for (int q = 0; q < 4; ++q) {
      uint2 e = cmb[tid * 4 + q];
      u32 m1 = min(b1, e.x);
      b2 = min(max(b1, e.x), min(b2, e.y));
      b1 = m1;
    }
    partials[(size_t)ct * M_TOK + row0 + tid] = make_uint2(b1, b2);
  }
}

// ---------------- global best-2 + flag near-ties ----------------
__global__ __launch_bounds__(256) void reduce_kernel(
    const uint2* __restrict__ partials, u32* __restrict__ bestkey,
    int* __restrict__ fidx, int* __restrict__ flaglist, int* __restrict__ cnt) {
  int t = blockIdx.x * 256 + threadIdx.x;
  if (t >= M_TOK) return;
  u32 b1 = 0xFFFFFFFFu, b2 = 0xFFFFFFFFu;
  int bidx = 0;
  for (int ct = 0; ct < 32; ++ct) {
    uint2 e = partials[(size_t)ct * M_TOK + t];
    if (e.x < b1) {
      b2 = min(b1, min(b2, e.y));
      b1 = e.x;
      bidx = ct * 256 + (int)(e.x & 255u);
    } else {
      b2 = min(b2, e.x);
    }
  }
  bestkey[t] = b1;
  fidx[t] = bidx;
  if (qval(b2) - qval(b1) < BAND) flaglist[atomicAdd(cnt, 1)] = t;
}

// ---------------- exact fp32 re-rank for flagged tokens ----------------
__global__ __launch_bounds__(256) void fixup_kernel(
    const float* __restrict__ xs, const float* __restrict__ w,
    const float* __restrict__ wnorm, const uint2* __restrict__ partials,
    const u32* __restrict__ bestkey, const int* __restrict__ flaglist,
    const int* __restrict__ cnt, int* __restrict__ fidx) {
  __shared__ int s_cand[8256];
  __shared__ int s_n;
  __shared__ u64 s_best;
  const int n_flag = *cnt;
  for (int ii = blockIdx.x; ii < n_flag; ii += gridDim.x) {
    const int t = flaglist[ii];
    if (threadIdx.x == 0) { s_n = 0; s_best = ~0ULL; }
    __syncthreads();
    const float thr = qval(bestkey[t]) + BAND;
    if (threadIdx.x < 32) {
      uint2 e = partials[(size_t)threadIdx.x * M_TOK + t];
      if (qval(e.x) <= thr)
        s_cand[atomicAdd(&s_n, 1)] = (int)threadIdx.x * 256 + (int)(e.x & 255u);
      if (qval(e.y) <= thr) {                // possible hidden 3rd: scan whole block
        int base = atomicAdd(&s_n, 256);
        for (int c = 0; c < 256; ++c) s_cand[base + c] = (int)threadIdx.x * 256 + c;
      }
    }
    __syncthreads();
    const int n = s_n;
    const int wid = threadIdx.x >> 6, lane = threadIdx.x & 63;
    for (int c = wid; c < n; c += 4) {
      const int j = s_cand[c];
      const float4* xr = (const float4*)(xs + (size_t)t * D_K);
      const float4* wr = (const float4*)(w + (size_t)j * D_K);
      float4 a0 = xr[lane * 2], a1 = xr[lane * 2 + 1];
      float4 b0 = wr[lane * 2], b1 = wr[lane * 2 + 1];
      float s = a0.x*b0.x + a0.y*b0.y + a0.z*b0.z + a0.w*b0.w
              + a1.x*b1.x + a1.y*b1.y + a1.z*b1.z + a1.w*b1.w;
      #pragma unroll
      for (int off = 32; off; off >>= 1) s += __shfl_xor(s, off);
      if (lane == 0) {
        float score = wnorm[j] - 2.0f * s;
        u64 k = ((u64)map_f(score) << 32) | (u32)j;
        atomicMin(&s_best, k);
      }
    }
    __syncthreads();
    if (threadIdx.x == 0) fidx[t] = (int)(s_best & 0xFFFFFFFFULL);
    __syncthreads();
  }
}

// ---------------- gather: out = xs + (W[idx] - xs) ----------------
__global__ __launch_bounds__(256) void gather_kernel(const float* __restrict__ xs,
                                                     const float* __restrict__ w,
                                                     const int* __restrict__ fidx,
                                                     float* __restrict__ out) {
  int e = blockIdx.x * 256 + threadIdx.x;
  int row = e >> 7, off = e & 127;
  float4 xv = ((const float4*)(xs + (size_t)row * D_K))[off];
  float4 wv = ((const float4*)(w  + (size_t)fidx[row] * D_K))[off];
  float4 o;
  o.x = xv.x + (wv.x - xv.x);
  o.y = xv.y + (wv.y - xv.y);
  o.z = xv.z + (wv.z - xv.z);
  o.w = xv.w + (wv.w - xv.w);
  ((float4*)out)[e] = o;
}

extern "C" void kernel_launch(void* const* d_in, const int* in_sizes, int n_in,
                              void* d_out, int out_size, void* d_ws, size_t ws_size,
                              hipStream_t stream) {
  const float* xs = (const float*)d_in[0];
  const float* w  = (const float*)d_in[1];
  float* out = (float*)d_out;

  // ws layout (~51 MB; ws proven >= 85 MB in R2)
  char* p = (char*)d_ws;
  f16*   Xh       = (f16*)p;                 p += (size_t)M_TOK * D_K * 2;
  f16*   Wh       = (f16*)p;                 p += (size_t)N_EMB * D_K * 2;
  float* wnorm    = (float*)p;               p += (size_t)N_EMB * 4;
  uint2* partials = (uint2*)p;               p += (size_t)32 * M_TOK * 8;
  u32*   bestkey  = (u32*)p;                 p += (size_t)M_TOK * 4;
  int*   fidx     = (int*)p;                 p += (size_t)M_TOK * 4;
  int*   flaglist = (int*)p;                 p += (size_t)M_TOK * 4;
  int*   cnt      = (int*)p;

  convert_hi_kernel<<<(M_TOK * 128) / 256, 256, 0, stream>>>(xs, Xh, M_TOK * 128);
  convw_norm_kernel<<<N_EMB / 4, 256, 0, stream>>>(w, Wh, wnorm, cnt);
  dist_mfma_kernel<<<(M_TOK / 128) * (N_EMB / 256), 256, 0, stream>>>(Xh, Wh, wnorm, partials);
  reduce_kernel<<<M_TOK / 256, 256, 0, stream>>>(partials, bestkey, fidx, flaglist, cnt);
  fixup_kernel<<<256, 256, 0, stream>>>(xs, w, wnorm, partials, bestkey, flaglist, cnt, fidx);
  gather_kernel<<<(M_TOK * (D_K / 4)) / 256, 256, 0, stream>>>(xs, w, fidx, out);
}